// Round 2
// baseline (2640.294 us; speedup 1.0000x reference)
//
#include <hip/hip_runtime.h>
#include <hip/hip_bf16.h>

#define HDIM 32
#define NLAYERS 4

// ---------------- zero fill (graph-capture-safe memset) ----------------
__global__ void zero_kernel(float4* __restrict__ p, size_t n4)
{
    size_t stride = (size_t)gridDim.x * 256;
    for (size_t i = (size_t)blockIdx.x * 256 + threadIdx.x; i < n4; i += stride)
        p[i] = make_float4(0.f, 0.f, 0.f, 0.f);
}

// ---------------- init projection: out[i] = in[i>>5]*w[j] + b[j] ----------------
__global__ void init_proj(const float* __restrict__ in, const float* __restrict__ w,
                          const float* __restrict__ b, float* __restrict__ out, size_t total)
{
    size_t i = (size_t)blockIdx.x * 256 + threadIdx.x;
    if (i < total) {
        int j = (int)(i & 31);
        out[i] = fmaf(in[i >> 5], w[j], b[j]);
    }
}

// ---------------- fused node GEMMs: Ah,Bh,Uh,Vh = h @ {A,B,U,V} + bias ----------------
__global__ __launch_bounds__(256) void node_gemm(
    const float* __restrict__ h,
    const float* __restrict__ Aw, const float* __restrict__ Ab,
    const float* __restrict__ Bw, const float* __restrict__ Bb,
    const float* __restrict__ Uw, const float* __restrict__ Ub,
    const float* __restrict__ Vw, const float* __restrict__ Vb,
    float* __restrict__ Ahh, float* __restrict__ Bhh,
    float* __restrict__ Uhh, float* __restrict__ Vhh, int N)
{
    __shared__ float wA[1024], wB[1024], wU[1024], wV[1024];
    __shared__ float bA[32], bB[32], bU[32], bV[32];
    __shared__ float lh[256];
    int tid = threadIdx.x;
    for (int i = tid; i < 1024; i += 256) { wA[i] = Aw[i]; wB[i] = Bw[i]; wU[i] = Uw[i]; wV[i] = Vw[i]; }
    if (tid < 32) { bA[tid] = Ab[tid]; bB[tid] = Bb[tid]; bU[tid] = Ub[tid]; bV[tid] = Vb[tid]; }
    int j = tid & 31, el = tid >> 5;
    int ng = (N + 7) >> 3;
    for (int g = blockIdx.x; g < ng; g += gridDim.x) {
        int base = g << 3;
        int nid = base + el;
        __syncthreads();
        if (nid < N) lh[tid] = h[(size_t)base * 32 + tid];
        __syncthreads();
        if (nid < N) {
            float a = bA[j], b = bB[j], u = bU[j], v = bV[j];
#pragma unroll
            for (int k = 0; k < 32; k++) {
                float hk = lh[el * 32 + k];
                a = fmaf(hk, wA[k * 32 + j], a);
                b = fmaf(hk, wB[k * 32 + j], b);
                u = fmaf(hk, wU[k * 32 + j], u);
                v = fmaf(hk, wV[k * 32 + j], v);
            }
            size_t o = (size_t)nid * 32 + j;
            Ahh[o] = a; Bhh[o] = b; Uhh[o] = u; Vhh[o] = v;
        }
    }
}

// ---- edge pass 1: Ce GEMM + gather + sigmoid + atomic scatter + BN partials (no enew store) ----
__global__ __launch_bounds__(256) void edge_kernel(
    const float* __restrict__ e, const int* __restrict__ srcs, const int* __restrict__ dsts,
    const float* __restrict__ Ah, const float* __restrict__ Bh, const float* __restrict__ Vh,
    const float* __restrict__ Cw, const float* __restrict__ Cb,
    float* __restrict__ num, float* __restrict__ den,
    float* __restrict__ part, int E)
{
    __shared__ float lw[1024];
    __shared__ float lb[32];
    __shared__ float le[256];
    __shared__ int lsrc[8], ldst[8];
    __shared__ float red[256];
    int tid = threadIdx.x;
    for (int i = tid; i < 1024; i += 256) lw[i] = Cw[i];
    if (tid < 32) lb[tid] = Cb[tid];
    int j = tid & 31, el = tid >> 5;
    float lsum = 0.f, lsq = 0.f;
    int ng = (E + 7) >> 3;
    for (int g = blockIdx.x; g < ng; g += gridDim.x) {
        int base = g << 3;
        int eid = base + el;
        __syncthreads();
        if (eid < E) le[tid] = e[(size_t)base * 32 + tid];
        if (tid < 8) {
            int ee = base + tid;
            if (ee < E) { lsrc[tid] = srcs[ee]; ldst[tid] = dsts[ee]; }
        }
        __syncthreads();
        if (eid < E) {
            float acc = lb[j];
#pragma unroll
            for (int k = 0; k < 32; k++) acc = fmaf(le[el * 32 + k], lw[k * 32 + j], acc);
            int s = lsrc[el], d = ldst[el];
            float en = acc + Ah[(size_t)d * 32 + j] + Bh[(size_t)s * 32 + j];
            float sg = 1.f / (1.f + __expf(-en));
            atomicAdd(&num[(size_t)d * 32 + j], sg * Vh[(size_t)s * 32 + j]);
            atomicAdd(&den[(size_t)d * 32 + j], sg);
            lsum += en; lsq += en * en;
        }
    }
    __syncthreads();
    red[tid] = lsum;
    __syncthreads();
    if (el == 0) {
        float s = 0.f;
        for (int r = 0; r < 8; r++) s += red[r * 32 + j];
        part[(size_t)blockIdx.x * 64 + j] = s;
    }
    __syncthreads();
    red[tid] = lsq;
    __syncthreads();
    if (el == 0) {
        float s = 0.f;
        for (int r = 0; r < 8; r++) s += red[r * 32 + j];
        part[(size_t)blockIdx.x * 64 + 32 + j] = s;
    }
}

// ---- node update: num <- Uh + num/(den+eps) (in place), BN partials ----
__global__ __launch_bounds__(256) void node_update(
    const float* __restrict__ Uh, float* __restrict__ num, const float* __restrict__ den,
    float* __restrict__ part, int N)
{
    __shared__ float red[256];
    int tid = threadIdx.x;
    int j = tid & 31;
    size_t total = (size_t)N * 32;
    float lsum = 0.f, lsq = 0.f;
    for (size_t i = (size_t)blockIdx.x * 256 + tid; i < total; i += (size_t)gridDim.x * 256) {
        float v = Uh[i] + num[i] / (den[i] + 1e-6f);
        num[i] = v;
        lsum += v; lsq += v * v;
    }
    red[tid] = lsum;
    __syncthreads();
    if (tid < 32) {
        float s = 0.f;
        for (int r = 0; r < 8; r++) s += red[r * 32 + j];
        part[(size_t)blockIdx.x * 64 + j] = s;
    }
    __syncthreads();
    red[tid] = lsq;
    __syncthreads();
    if (tid < 32) {
        float s = 0.f;
        for (int r = 0; r < 8; r++) s += red[r * 32 + j];
        part[(size_t)blockIdx.x * 64 + 32 + j] = s;
    }
}

// ---------------- finalize BN stats (double accumulation) ----------------
__global__ __launch_bounds__(256) void stats_finalize(
    const float* __restrict__ pA, int nA, double cntA, const float* __restrict__ gA, const float* __restrict__ bA,
    float* __restrict__ scA, float* __restrict__ shA,
    const float* __restrict__ pB, int nB, double cntB, const float* __restrict__ gB, const float* __restrict__ bB,
    float* __restrict__ scB, float* __restrict__ shB)
{
    const float* p; int n; double cnt; const float* g; const float* b; float* sc; float* sh;
    if (blockIdx.x == 0) { p = pA; n = nA; cnt = cntA; g = gA; b = bA; sc = scA; sh = shA; }
    else                 { p = pB; n = nB; cnt = cntB; g = gB; b = bB; sc = scB; sh = shB; }
    __shared__ double red[256];
    int tid = threadIdx.x;
    int col = tid & 63, row0 = tid >> 6;
    double s = 0.0;
    for (int r = row0; r < n; r += 4) s += (double)p[(size_t)r * 64 + col];
    red[tid] = s;
    __syncthreads();
    if (tid < 64) red[tid] = red[tid] + red[64 + tid] + red[128 + tid] + red[192 + tid];
    __syncthreads();
    if (tid < 32) {
        double sum = red[tid], sq = red[32 + tid];
        double mean = sum / cnt;
        double var = sq / cnt - mean * mean;
        float scale = g[tid] * (float)(1.0 / sqrt(var + 1e-5));
        sc[tid] = scale;
        sh[tid] = b[tid] - (float)mean * scale;
    }
}

// ---------------- apply (h): acc += relu(pre*scale + shift) ----------------
__global__ void apply_kernel(const float* __restrict__ pre, const float* __restrict__ scale,
                             const float* __restrict__ shift, float* __restrict__ acc, size_t total)
{
    size_t i = (size_t)blockIdx.x * 256 + threadIdx.x;
    if (i < total) {
        int j = (int)(i & 31);
        float v = fmaf(pre[i], scale[j], shift[j]);
        acc[i] += fmaxf(v, 0.f);
    }
}

// ---- edge pass 2: recompute e_new (same FMA order), apply BN+ReLU+residual in place ----
__global__ __launch_bounds__(256) void apply_e_fused(
    float* __restrict__ e, const int* __restrict__ srcs, const int* __restrict__ dsts,
    const float* __restrict__ Ah, const float* __restrict__ Bh,
    const float* __restrict__ Cw, const float* __restrict__ Cb,
    const float* __restrict__ sc, const float* __restrict__ sh, int E)
{
    __shared__ float lw[1024];
    __shared__ float lb[32];
    __shared__ float le[256];
    __shared__ int lsrc[8], ldst[8];
    int tid = threadIdx.x;
    for (int i = tid; i < 1024; i += 256) lw[i] = Cw[i];
    if (tid < 32) lb[tid] = Cb[tid];
    int j = tid & 31, el = tid >> 5;
    float scale = sc[j], shift = sh[j];
    int ng = (E + 7) >> 3;
    for (int g = blockIdx.x; g < ng; g += gridDim.x) {
        int base = g << 3;
        int eid = base + el;
        __syncthreads();
        if (eid < E) le[tid] = e[(size_t)base * 32 + tid];
        if (tid < 8) {
            int ee = base + tid;
            if (ee < E) { lsrc[tid] = srcs[ee]; ldst[tid] = dsts[ee]; }
        }
        __syncthreads();
        if (eid < E) {
            float acc = lb[j];
#pragma unroll
            for (int k = 0; k < 32; k++) acc = fmaf(le[el * 32 + k], lw[k * 32 + j], acc);
            int s = lsrc[el], d = ldst[el];
            float en = acc + Ah[(size_t)d * 32 + j] + Bh[(size_t)s * 32 + j];
            float v = fmaf(en, scale, shift);
            e[(size_t)eid * 32 + j] = le[el * 32 + j] + fmaxf(v, 0.f);
        }
    }
}

// ---------------- predictor: relu([h[src],h[dst],e] @ W1 + b1) @ W2 + b2 ----------------
__global__ __launch_bounds__(256) void predictor(
    const float* __restrict__ h, const float* __restrict__ e,
    const int* __restrict__ srcs, const int* __restrict__ dsts,
    const float* __restrict__ W1, const float* __restrict__ b1,
    const float* __restrict__ W2, const float* __restrict__ b2v,
    float* __restrict__ out, int E)
{
    __shared__ float w1[96 * 32];
    __shared__ float lb1[32];
    __shared__ float w2[32];
    __shared__ float z[8][96];
    int tid = threadIdx.x;
    for (int i = tid; i < 96 * 32; i += 256) w1[i] = W1[i];
    if (tid < 32) { lb1[tid] = b1[tid]; w2[tid] = W2[tid]; }
    float b2 = b2v[0];
    int j = tid & 31, el = tid >> 5;
    int ng = (E + 7) >> 3;
    for (int g = blockIdx.x; g < ng; g += gridDim.x) {
        int base = g << 3;
        int eid = base + el;
        __syncthreads();
        if (eid < E) {
            int s = srcs[eid], d = dsts[eid];
            z[el][j]      = h[(size_t)s * 32 + j];
            z[el][32 + j] = h[(size_t)d * 32 + j];
            z[el][64 + j] = e[(size_t)eid * 32 + j];
        }
        __syncthreads();
        if (eid < E) {
            float t = lb1[j];
#pragma unroll
            for (int k = 0; k < 96; k++) t = fmaf(z[el][k], w1[k * 32 + j], t);
            t = fmaxf(t, 0.f) * w2[j];
#pragma unroll
            for (int off = 16; off; off >>= 1) t += __shfl_down(t, off, 32);
            if (j == 0) out[eid] = t + b2;
        }
    }
}

extern "C" void kernel_launch(void* const* d_in, const int* in_sizes, int n_in,
                              void* d_out, int out_size, void* d_ws, size_t ws_size,
                              hipStream_t stream)
{
    const int N = in_sizes[0];
    const int E = in_sizes[1];

    const float* x    = (const float*)d_in[0];
    const float* e_in = (const float*)d_in[1];
    const int*   eidx = (const int*)d_in[2];
    const float* pe_w = (const float*)d_in[3];
    const float* pe_b = (const float*)d_in[4];
    const float* ed_w = (const float*)d_in[5];
    const float* ed_b = (const float*)d_in[6];
    const float* Aw = (const float*)d_in[7];
    const float* Ab = (const float*)d_in[8];
    const float* Bw = (const float*)d_in[9];
    const float* Bb = (const float*)d_in[10];
    const float* Cw = (const float*)d_in[11];
    const float* Cb = (const float*)d_in[12];
    const float* Uw = (const float*)d_in[13];
    const float* Ub = (const float*)d_in[14];
    const float* Vw = (const float*)d_in[15];
    const float* Vb = (const float*)d_in[16];
    const float* bn_h_g = (const float*)d_in[17];
    const float* bn_h_b = (const float*)d_in[18];
    const float* bn_e_g = (const float*)d_in[19];
    const float* bn_e_b = (const float*)d_in[20];
    const float* W1w = (const float*)d_in[21];
    const float* W1b = (const float*)d_in[22];
    const float* W2w = (const float*)d_in[23];
    const float* W2b = (const float*)d_in[24];

    const int* srcs = eidx;
    const int* dsts = eidx + E;

    size_t nh = (size_t)N * 32;
    size_t eh = (size_t)E * 32;

    float* ws = (float*)d_ws;
    float* h    = ws;
    float* Ah   = h + nh;
    float* Bh   = Ah + nh;
    float* Uh   = Bh + nh;
    float* Vh   = Uh + nh;
    float* num  = Vh + nh;        // doubles as hnew (in-place)
    float* den  = num + nh;       // num & den contiguous for one zero-fill
    float* e    = den + nh;
    float* part_h = e + eh;              // 2048*64
    float* part_e = part_h + 2048 * 64;  // 4096*64
    float* stats  = part_e + 4096 * 64;  // sc_h[32],sh_h[32],sc_e[32],sh_e[32]

    int gh = (int)((nh + 255) / 256);
    int ge = (int)((eh + 255) / 256);

    init_proj<<<gh, 256, 0, stream>>>(x, pe_w, pe_b, h, nh);
    init_proj<<<ge, 256, 0, stream>>>(e_in, ed_w, ed_b, e, eh);

    for (int l = 0; l < NLAYERS; l++) {
        zero_kernel<<<1024, 256, 0, stream>>>((float4*)num, (2 * nh) / 4);
        node_gemm<<<2048, 256, 0, stream>>>(h,
            Aw + l * 1024, Ab + l * 32,
            Bw + l * 1024, Bb + l * 32,
            Uw + l * 1024, Ub + l * 32,
            Vw + l * 1024, Vb + l * 32,
            Ah, Bh, Uh, Vh, N);
        edge_kernel<<<4096, 256, 0, stream>>>(e, srcs, dsts, Ah, Bh, Vh,
            Cw + l * 1024, Cb + l * 32, num, den, part_e, E);
        node_update<<<2048, 256, 0, stream>>>(Uh, num, den, part_h, N);
        stats_finalize<<<2, 256, 0, stream>>>(
            part_h, 2048, (double)N, bn_h_g + l * 32, bn_h_b + l * 32, stats + 0,  stats + 32,
            part_e, 4096, (double)E, bn_e_g + l * 32, bn_e_b + l * 32, stats + 64, stats + 96);
        apply_kernel<<<gh, 256, 0, stream>>>(num, stats + 0,  stats + 32, h, nh);
        apply_e_fused<<<4096, 256, 0, stream>>>(e, srcs, dsts, Ah, Bh,
            Cw + l * 1024, Cb + l * 32, stats + 64, stats + 96, E);
    }

    predictor<<<4096, 256, 0, stream>>>(h, e, srcs, dsts, W1w, W1b, W2w, W2b, (float*)d_out, E);
}

// Round 3
// 2513.033 us; speedup vs baseline: 1.0506x; 1.0506x over previous
//
#include <hip/hip_runtime.h>
#include <hip/hip_bf16.h>

#define NLAYERS 4

// ---------------- zero fill (graph-capture-safe memset) ----------------
__global__ void zero_kernel(float4* __restrict__ p, size_t n4)
{
    size_t stride = (size_t)gridDim.x * 256;
    for (size_t i = (size_t)blockIdx.x * 256 + threadIdx.x; i < n4; i += stride)
        p[i] = make_float4(0.f, 0.f, 0.f, 0.f);
}

// ---------------- init projection (float4): out[node][j] = in[node]*w[j] + b[j] ----------------
__global__ void init_proj4(const float* __restrict__ in, const float* __restrict__ w,
                           const float* __restrict__ b, float4* __restrict__ out, size_t n4)
{
    size_t i = (size_t)blockIdx.x * 256 + threadIdx.x;
    if (i < n4) {
        int j4 = (int)(i & 7) * 4;
        float xv = in[i >> 3];
        float4 wv = *(const float4*)(w + j4);
        float4 bv = *(const float4*)(b + j4);
        out[i] = make_float4(fmaf(xv, wv.x, bv.x), fmaf(xv, wv.y, bv.y),
                             fmaf(xv, wv.z, bv.z), fmaf(xv, wv.w, bv.w));
    }
}

// ---------------- node GEMMs: one node per thread, scalar-broadcast weights ----------------
__device__ __forceinline__ void mat32(const float* __restrict__ hrow,
                                      const float* __restrict__ W, const float* __restrict__ Wb,
                                      float* __restrict__ dst)
{
    float acc[32];
#pragma unroll
    for (int j = 0; j < 32; j++) acc[j] = Wb[j];          // uniform -> s_load
#pragma unroll 4
    for (int k = 0; k < 32; k++) {
        float hk = hrow[k];
#pragma unroll
        for (int j = 0; j < 32; j++) acc[j] = fmaf(hk, W[k * 32 + j], acc[j]);  // sgpr operand
    }
    float4* o = (float4*)dst;
#pragma unroll
    for (int q = 0; q < 8; q++) o[q] = make_float4(acc[4*q], acc[4*q+1], acc[4*q+2], acc[4*q+3]);
}

__global__ __launch_bounds__(64) void node_gemm(
    const float* __restrict__ h,
    const float* __restrict__ Aw, const float* __restrict__ Ab,
    const float* __restrict__ Bw, const float* __restrict__ Bb,
    const float* __restrict__ Uw, const float* __restrict__ Ub,
    const float* __restrict__ Vw, const float* __restrict__ Vb,
    float* __restrict__ Ahh, float* __restrict__ Bhh,
    float* __restrict__ Uhh, float* __restrict__ Vhh, int N)
{
    int nid = blockIdx.x * 64 + threadIdx.x;
    if (nid >= N) return;
    const float* hrow = h + (size_t)nid * 32;
    size_t o = (size_t)nid * 32;
    mat32(hrow, Aw, Ab, Ahh + o);
    mat32(hrow, Bw, Bb, Bhh + o);
    mat32(hrow, Uw, Ub, Uhh + o);
    mat32(hrow, Vw, Vb, Vhh + o);
}

// ---- edge pass 1: Ce GEMM (reg weights + b128 LDS) + gather + sigmoid + atomics + BN partials ----
__global__ __launch_bounds__(256) void edge_kernel(
    const float* __restrict__ e, const int* __restrict__ srcs, const int* __restrict__ dsts,
    const float* __restrict__ Ah, const float* __restrict__ Bh, const float* __restrict__ Vh,
    const float* __restrict__ Cw, const float* __restrict__ Cb,
    float* __restrict__ num, float* __restrict__ den,
    float* __restrict__ part, int E)
{
    __shared__ float le[256];
    __shared__ int lsrc[8], ldst[8];
    __shared__ float red[256];
    int tid = threadIdx.x, j = tid & 31, el = tid >> 5;
    float cw[32];
#pragma unroll
    for (int k = 0; k < 32; k++) cw[k] = Cw[k * 32 + j];
    float cb = Cb[j];
    float lsum = 0.f, lsq = 0.f;
    int ng = (E + 7) >> 3;
    for (int g = blockIdx.x; g < ng; g += gridDim.x) {
        int base = g << 3;
        __syncthreads();
        if (tid < 64) {
            int row = base + (tid >> 3);
            if (row < E) ((float4*)le)[tid] = ((const float4*)(e + (size_t)base * 32))[tid];
        }
        if (tid < 8) {
            int ee = base + tid;
            if (ee < E) { lsrc[tid] = srcs[ee]; ldst[tid] = dsts[ee]; }
        }
        __syncthreads();
        int eid = base + el;
        if (eid < E) {
            const float4* lr = (const float4*)(le + el * 32);
            float acc = cb;
#pragma unroll
            for (int q = 0; q < 8; q++) {
                float4 ev = lr[q];
                acc = fmaf(ev.x, cw[4*q],   acc);
                acc = fmaf(ev.y, cw[4*q+1], acc);
                acc = fmaf(ev.z, cw[4*q+2], acc);
                acc = fmaf(ev.w, cw[4*q+3], acc);
            }
            int s = lsrc[el], d = ldst[el];
            float en = acc + Ah[(size_t)d * 32 + j] + Bh[(size_t)s * 32 + j];
            float sg = 1.f / (1.f + __expf(-en));
            atomicAdd(&num[(size_t)d * 32 + j], sg * Vh[(size_t)s * 32 + j]);
            atomicAdd(&den[(size_t)d * 32 + j], sg);
            lsum += en; lsq += en * en;
        }
    }
    __syncthreads();
    red[tid] = lsum;
    __syncthreads();
    if (el == 0) {
        float s = 0.f;
        for (int r = 0; r < 8; r++) s += red[r * 32 + j];
        part[(size_t)blockIdx.x * 64 + j] = s;
    }
    __syncthreads();
    red[tid] = lsq;
    __syncthreads();
    if (el == 0) {
        float s = 0.f;
        for (int r = 0; r < 8; r++) s += red[r * 32 + j];
        part[(size_t)blockIdx.x * 64 + 32 + j] = s;
    }
}

// ---- node update (float4): num <- Uh + num/(den+eps) in place, BN partials ----
__global__ __launch_bounds__(256) void node_update(
    const float4* __restrict__ Uh4, float4* __restrict__ num4, const float4* __restrict__ den4,
    float* __restrict__ part, int N)
{
    __shared__ float red[1024];
    int tid = threadIdx.x;
    size_t n4 = (size_t)N * 8;
    float4 ls = make_float4(0,0,0,0), lq = make_float4(0,0,0,0);
    for (size_t i = (size_t)blockIdx.x * 256 + tid; i < n4; i += (size_t)gridDim.x * 256) {
        float4 u = Uh4[i], nu = num4[i], de = den4[i];
        float4 v;
        v.x = u.x + nu.x / (de.x + 1e-6f);
        v.y = u.y + nu.y / (de.y + 1e-6f);
        v.z = u.z + nu.z / (de.z + 1e-6f);
        v.w = u.w + nu.w / (de.w + 1e-6f);
        num4[i] = v;
        ls.x += v.x; ls.y += v.y; ls.z += v.z; ls.w += v.w;
        lq.x += v.x*v.x; lq.y += v.y*v.y; lq.z += v.z*v.z; lq.w += v.w*v.w;
    }
    red[tid*4+0] = ls.x; red[tid*4+1] = ls.y; red[tid*4+2] = ls.z; red[tid*4+3] = ls.w;
    __syncthreads();
    if (tid < 32) {
        int gj = tid >> 2, comp = tid & 3;
        float s = 0.f;
        for (int r = 0; r < 32; r++) s += red[(r * 8 + gj) * 4 + comp];
        part[(size_t)blockIdx.x * 64 + tid] = s;
    }
    __syncthreads();
    red[tid*4+0] = lq.x; red[tid*4+1] = lq.y; red[tid*4+2] = lq.z; red[tid*4+3] = lq.w;
    __syncthreads();
    if (tid < 32) {
        int gj = tid >> 2, comp = tid & 3;
        float s = 0.f;
        for (int r = 0; r < 32; r++) s += red[(r * 8 + gj) * 4 + comp];
        part[(size_t)blockIdx.x * 64 + 32 + tid] = s;
    }
}

// ---------------- finalize BN stats (double accumulation) ----------------
__global__ __launch_bounds__(256) void stats_finalize(
    const float* __restrict__ pA, int nA, double cntA, const float* __restrict__ gA, const float* __restrict__ bA,
    float* __restrict__ scA, float* __restrict__ shA,
    const float* __restrict__ pB, int nB, double cntB, const float* __restrict__ gB, const float* __restrict__ bB,
    float* __restrict__ scB, float* __restrict__ shB)
{
    const float* p; int n; double cnt; const float* g; const float* b; float* sc; float* sh;
    if (blockIdx.x == 0) { p = pA; n = nA; cnt = cntA; g = gA; b = bA; sc = scA; sh = shA; }
    else                 { p = pB; n = nB; cnt = cntB; g = gB; b = bB; sc = scB; sh = shB; }
    __shared__ double red[256];
    int tid = threadIdx.x;
    int col = tid & 63, row0 = tid >> 6;
    double s = 0.0;
    for (int r = row0; r < n; r += 4) s += (double)p[(size_t)r * 64 + col];
    red[tid] = s;
    __syncthreads();
    if (tid < 64) red[tid] = red[tid] + red[64 + tid] + red[128 + tid] + red[192 + tid];
    __syncthreads();
    if (tid < 32) {
        double sum = red[tid], sq = red[32 + tid];
        double mean = sum / cnt;
        double var = sq / cnt - mean * mean;
        float scale = g[tid] * (float)(1.0 / sqrt(var + 1e-5));
        sc[tid] = scale;
        sh[tid] = b[tid] - (float)mean * scale;
    }
}

// ---------------- apply (h, float4): acc += relu(pre*scale + shift) ----------------
__global__ void apply4(const float4* __restrict__ pre, const float* __restrict__ scale,
                       const float* __restrict__ shift, float4* __restrict__ acc, size_t n4)
{
    size_t i = (size_t)blockIdx.x * 256 + threadIdx.x;
    if (i < n4) {
        int j4 = (int)(i & 7) * 4;
        float4 sc = *(const float4*)(scale + j4);
        float4 sh = *(const float4*)(shift + j4);
        float4 p = pre[i], a = acc[i];
        a.x += fmaxf(fmaf(p.x, sc.x, sh.x), 0.f);
        a.y += fmaxf(fmaf(p.y, sc.y, sh.y), 0.f);
        a.z += fmaxf(fmaf(p.z, sc.z, sh.z), 0.f);
        a.w += fmaxf(fmaf(p.w, sc.w, sh.w), 0.f);
        acc[i] = a;
    }
}

// ---- edge pass 2: recompute e_new (same FMA order), apply BN+ReLU+residual in place ----
__global__ __launch_bounds__(256) void apply_e_fused(
    float* __restrict__ e, const int* __restrict__ srcs, const int* __restrict__ dsts,
    const float* __restrict__ Ah, const float* __restrict__ Bh,
    const float* __restrict__ Cw, const float* __restrict__ Cb,
    const float* __restrict__ sc, const float* __restrict__ sh, int E)
{
    __shared__ float le[256];
    __shared__ int lsrc[8], ldst[8];
    int tid = threadIdx.x, j = tid & 31, el = tid >> 5;
    float cw[32];
#pragma unroll
    for (int k = 0; k < 32; k++) cw[k] = Cw[k * 32 + j];
    float cb = Cb[j];
    float scale = sc[j], shift = sh[j];
    int ng = (E + 7) >> 3;
    for (int g = blockIdx.x; g < ng; g += gridDim.x) {
        int base = g << 3;
        __syncthreads();
        if (tid < 64) {
            int row = base + (tid >> 3);
            if (row < E) ((float4*)le)[tid] = ((const float4*)(e + (size_t)base * 32))[tid];
        }
        if (tid < 8) {
            int ee = base + tid;
            if (ee < E) { lsrc[tid] = srcs[ee]; ldst[tid] = dsts[ee]; }
        }
        __syncthreads();
        int eid = base + el;
        if (eid < E) {
            const float4* lr = (const float4*)(le + el * 32);
            float acc = cb;
#pragma unroll
            for (int q = 0; q < 8; q++) {
                float4 ev = lr[q];
                acc = fmaf(ev.x, cw[4*q],   acc);
                acc = fmaf(ev.y, cw[4*q+1], acc);
                acc = fmaf(ev.z, cw[4*q+2], acc);
                acc = fmaf(ev.w, cw[4*q+3], acc);
            }
            int s = lsrc[el], d = ldst[el];
            float en = acc + Ah[(size_t)d * 32 + j] + Bh[(size_t)s * 32 + j];
            float v = fmaf(en, scale, shift);
            e[(size_t)eid * 32 + j] = le[el * 32 + j] + fmaxf(v, 0.f);
        }
    }
}

// ---------------- predictor: one edge per thread, scalar-broadcast W1/W2 ----------------
__global__ __launch_bounds__(256) void predictor(
    const float* __restrict__ h, const float* __restrict__ e,
    const int* __restrict__ srcs, const int* __restrict__ dsts,
    const float* __restrict__ W1, const float* __restrict__ b1,
    const float* __restrict__ W2, const float* __restrict__ b2v,
    float* __restrict__ out, int E)
{
    int eid = blockIdx.x * 256 + threadIdx.x;
    if (eid >= E) return;
    int s = srcs[eid], d = dsts[eid];
    float acc[32];
#pragma unroll
    for (int j = 0; j < 32; j++) acc[j] = b1[j];          // uniform -> s_load
    const float* zs = h + (size_t)s * 32;
    const float* zd = h + (size_t)d * 32;
    const float* ze = e + (size_t)eid * 32;
#pragma unroll 4
    for (int k = 0; k < 32; k++) {
        float zk = zs[k];
#pragma unroll
        for (int j = 0; j < 32; j++) acc[j] = fmaf(zk, W1[k * 32 + j], acc[j]);
    }
#pragma unroll 4
    for (int k = 0; k < 32; k++) {
        float zk = zd[k];
#pragma unroll
        for (int j = 0; j < 32; j++) acc[j] = fmaf(zk, W1[(32 + k) * 32 + j], acc[j]);
    }
#pragma unroll 4
    for (int k = 0; k < 32; k++) {
        float zk = ze[k];
#pragma unroll
        for (int j = 0; j < 32; j++) acc[j] = fmaf(zk, W1[(64 + k) * 32 + j], acc[j]);
    }
    float t = b2v[0];
#pragma unroll
    for (int j = 0; j < 32; j++) t += fmaxf(acc[j], 0.f) * W2[j];
    out[eid] = t;
}

extern "C" void kernel_launch(void* const* d_in, const int* in_sizes, int n_in,
                              void* d_out, int out_size, void* d_ws, size_t ws_size,
                              hipStream_t stream)
{
    const int N = in_sizes[0];
    const int E = in_sizes[1];

    const float* x    = (const float*)d_in[0];
    const float* e_in = (const float*)d_in[1];
    const int*   eidx = (const int*)d_in[2];
    const float* pe_w = (const float*)d_in[3];
    const float* pe_b = (const float*)d_in[4];
    const float* ed_w = (const float*)d_in[5];
    const float* ed_b = (const float*)d_in[6];
    const float* Aw = (const float*)d_in[7];
    const float* Ab = (const float*)d_in[8];
    const float* Bw = (const float*)d_in[9];
    const float* Bb = (const float*)d_in[10];
    const float* Cw = (const float*)d_in[11];
    const float* Cb = (const float*)d_in[12];
    const float* Uw = (const float*)d_in[13];
    const float* Ub = (const float*)d_in[14];
    const float* Vw = (const float*)d_in[15];
    const float* Vb = (const float*)d_in[16];
    const float* bn_h_g = (const float*)d_in[17];
    const float* bn_h_b = (const float*)d_in[18];
    const float* bn_e_g = (const float*)d_in[19];
    const float* bn_e_b = (const float*)d_in[20];
    const float* W1w = (const float*)d_in[21];
    const float* W1b = (const float*)d_in[22];
    const float* W2w = (const float*)d_in[23];
    const float* W2b = (const float*)d_in[24];

    const int* srcs = eidx;
    const int* dsts = eidx + E;

    size_t nh = (size_t)N * 32;
    size_t eh = (size_t)E * 32;

    float* ws = (float*)d_ws;
    float* h    = ws;
    float* Ah   = h + nh;
    float* Bh   = Ah + nh;
    float* Uh   = Bh + nh;
    float* Vh   = Uh + nh;
    float* num  = Vh + nh;        // doubles as hnew (in-place)
    float* den  = num + nh;       // num & den contiguous for one zero-fill
    float* e    = den + nh;
    float* part_h = e + eh;              // 2048*64
    float* part_e = part_h + 2048 * 64;  // 4096*64
    float* stats  = part_e + 4096 * 64;  // sc_h[32],sh_h[32],sc_e[32],sh_e[32]

    size_t nh4 = nh / 4, eh4 = eh / 4;
    int gh4 = (int)((nh4 + 255) / 256);
    int ge4 = (int)((eh4 + 255) / 256);

    init_proj4<<<gh4, 256, 0, stream>>>(x, pe_w, pe_b, (float4*)h, nh4);
    init_proj4<<<ge4, 256, 0, stream>>>(e_in, ed_w, ed_b, (float4*)e, eh4);

    for (int l = 0; l < NLAYERS; l++) {
        zero_kernel<<<1024, 256, 0, stream>>>((float4*)num, (2 * nh) / 4);
        node_gemm<<<(N + 63) / 64, 64, 0, stream>>>(h,
            Aw + l * 1024, Ab + l * 32,
            Bw + l * 1024, Bb + l * 32,
            Uw + l * 1024, Ub + l * 32,
            Vw + l * 1024, Vb + l * 32,
            Ah, Bh, Uh, Vh, N);
        edge_kernel<<<4096, 256, 0, stream>>>(e, srcs, dsts, Ah, Bh, Vh,
            Cw + l * 1024, Cb + l * 32, num, den, part_e, E);
        node_update<<<2048, 256, 0, stream>>>((const float4*)Uh, (float4*)num, (const float4*)den,
            part_h, N);
        stats_finalize<<<2, 256, 0, stream>>>(
            part_h, 2048, (double)N, bn_h_g + l * 32, bn_h_b + l * 32, stats + 0,  stats + 32,
            part_e, 4096, (double)E, bn_e_g + l * 32, bn_e_b + l * 32, stats + 64, stats + 96);
        apply4<<<gh4, 256, 0, stream>>>((const float4*)num, stats + 0, stats + 32, (float4*)h, nh4);
        apply_e_fused<<<4096, 256, 0, stream>>>(e, srcs, dsts, Ah, Bh,
            Cw + l * 1024, Cb + l * 32, stats + 64, stats + 96, E);
    }

    predictor<<<(E + 255) / 256, 256, 0, stream>>>(h, e, srcs, dsts, W1w, W1b, W2w, W2b,
                                                   (float*)d_out, E);
}

// Round 4
// 2090.634 us; speedup vs baseline: 1.2629x; 1.2020x over previous
//
#include <hip/hip_runtime.h>
#include <hip/hip_bf16.h>

#define NLAYERS 4

// ---------------- zero fill (graph-capture-safe memset) ----------------
__global__ void zero_kernel(float4* __restrict__ p, size_t n4)
{
    size_t stride = (size_t)gridDim.x * 256;
    for (size_t i = (size_t)blockIdx.x * 256 + threadIdx.x; i < n4; i += stride)
        p[i] = make_float4(0.f, 0.f, 0.f, 0.f);
}

// ---------------- init projection (float4): out[node][j] = in[node]*w[j] + b[j] ----------------
__global__ void init_proj4(const float* __restrict__ in, const float* __restrict__ w,
                           const float* __restrict__ b, float4* __restrict__ out, size_t n4)
{
    size_t i = (size_t)blockIdx.x * 256 + threadIdx.x;
    if (i < n4) {
        int j4 = (int)(i & 7) * 4;
        float xv = in[i >> 3];
        float4 wv = *(const float4*)(w + j4);
        float4 bv = *(const float4*)(b + j4);
        out[i] = make_float4(fmaf(xv, wv.x, bv.x), fmaf(xv, wv.y, bv.y),
                             fmaf(xv, wv.z, bv.z), fmaf(xv, wv.w, bv.w));
    }
}

// ---------------- node GEMMs: one node per thread, scalar-broadcast weights ----------------
__device__ __forceinline__ void mat32(const float* __restrict__ hrow,
                                      const float* __restrict__ W, const float* __restrict__ Wb,
                                      float* __restrict__ dst)
{
    float acc[32];
#pragma unroll
    for (int j = 0; j < 32; j++) acc[j] = Wb[j];          // uniform -> s_load
#pragma unroll 4
    for (int k = 0; k < 32; k++) {
        float hk = hrow[k];
#pragma unroll
        for (int j = 0; j < 32; j++) acc[j] = fmaf(hk, W[k * 32 + j], acc[j]);  // sgpr operand
    }
    float4* o = (float4*)dst;
#pragma unroll
    for (int q = 0; q < 8; q++) o[q] = make_float4(acc[4*q], acc[4*q+1], acc[4*q+2], acc[4*q+3]);
}

__global__ __launch_bounds__(64) void node_gemm(
    const float* __restrict__ h,
    const float* __restrict__ Aw, const float* __restrict__ Ab,
    const float* __restrict__ Bw, const float* __restrict__ Bb,
    const float* __restrict__ Uw, const float* __restrict__ Ub,
    const float* __restrict__ Vw, const float* __restrict__ Vb,
    float* __restrict__ Ahh, float* __restrict__ Bhh,
    float* __restrict__ Uhh, float* __restrict__ Vhh, int N)
{
    int nid = blockIdx.x * 64 + threadIdx.x;
    if (nid >= N) return;
    const float* hrow = h + (size_t)nid * 32;
    size_t o = (size_t)nid * 32;
    mat32(hrow, Aw, Ab, Ahh + o);
    mat32(hrow, Bw, Bb, Bhh + o);
    mat32(hrow, Uw, Ub, Uhh + o);
    mat32(hrow, Vw, Vb, Vhh + o);
}

// ---- edge pass 1: Ce GEMM (reg weights + b128 LDS) + gather + sigmoid + atomics + BN partials ----
__global__ __launch_bounds__(256) void edge_kernel(
    const float* __restrict__ e, const int* __restrict__ srcs, const int* __restrict__ dsts,
    const float* __restrict__ Ah, const float* __restrict__ Bh, const float* __restrict__ Vh,
    const float* __restrict__ Cw, const float* __restrict__ Cb,
    float* __restrict__ num, float* __restrict__ den,
    double* __restrict__ dacc, int E)
{
    __shared__ float le[256];
    __shared__ int lsrc[8], ldst[8];
    __shared__ float red[256];
    int tid = threadIdx.x, j = tid & 31, el = tid >> 5;
    float cw[32];
#pragma unroll
    for (int k = 0; k < 32; k++) cw[k] = Cw[k * 32 + j];
    float cb = Cb[j];
    float lsum = 0.f, lsq = 0.f;
    int ng = (E + 7) >> 3;
    for (int g = blockIdx.x; g < ng; g += gridDim.x) {
        int base = g << 3;
        __syncthreads();
        if (tid < 64) {
            int row = base + (tid >> 3);
            if (row < E) ((float4*)le)[tid] = ((const float4*)(e + (size_t)base * 32))[tid];
        }
        if (tid < 8) {
            int ee = base + tid;
            if (ee < E) { lsrc[tid] = srcs[ee]; ldst[tid] = dsts[ee]; }
        }
        __syncthreads();
        int eid = base + el;
        if (eid < E) {
            const float4* lr = (const float4*)(le + el * 32);
            float acc = cb;
#pragma unroll
            for (int q = 0; q < 8; q++) {
                float4 ev = lr[q];
                acc = fmaf(ev.x, cw[4*q],   acc);
                acc = fmaf(ev.y, cw[4*q+1], acc);
                acc = fmaf(ev.z, cw[4*q+2], acc);
                acc = fmaf(ev.w, cw[4*q+3], acc);
            }
            int s = lsrc[el], d = ldst[el];
            float en = acc + Ah[(size_t)d * 32 + j] + Bh[(size_t)s * 32 + j];
            float sg = 1.f / (1.f + __expf(-en));
            atomicAdd(&num[(size_t)d * 32 + j], sg * Vh[(size_t)s * 32 + j]);
            atomicAdd(&den[(size_t)d * 32 + j], sg);
            lsum += en; lsq += en * en;
        }
    }
    __syncthreads();
    red[tid] = lsum;
    __syncthreads();
    if (el == 0) {
        float s = 0.f;
        for (int r = 0; r < 8; r++) s += red[r * 32 + j];
        atomicAdd(&dacc[j], (double)s);
    }
    __syncthreads();
    red[tid] = lsq;
    __syncthreads();
    if (el == 0) {
        float s = 0.f;
        for (int r = 0; r < 8; r++) s += red[r * 32 + j];
        atomicAdd(&dacc[32 + j], (double)s);
    }
}

// ---- node update (float4): num <- Uh + num/(den+eps) in place, BN stat atomics ----
__global__ __launch_bounds__(256) void node_update(
    const float4* __restrict__ Uh4, float4* __restrict__ num4, const float4* __restrict__ den4,
    double* __restrict__ dacc, int N)
{
    __shared__ float red[1024];
    int tid = threadIdx.x;
    size_t n4 = (size_t)N * 8;
    float4 ls = make_float4(0,0,0,0), lq = make_float4(0,0,0,0);
    for (size_t i = (size_t)blockIdx.x * 256 + tid; i < n4; i += (size_t)gridDim.x * 256) {
        float4 u = Uh4[i], nu = num4[i], de = den4[i];
        float4 v;
        v.x = u.x + nu.x / (de.x + 1e-6f);
        v.y = u.y + nu.y / (de.y + 1e-6f);
        v.z = u.z + nu.z / (de.z + 1e-6f);
        v.w = u.w + nu.w / (de.w + 1e-6f);
        num4[i] = v;
        ls.x += v.x; ls.y += v.y; ls.z += v.z; ls.w += v.w;
        lq.x += v.x*v.x; lq.y += v.y*v.y; lq.z += v.z*v.z; lq.w += v.w*v.w;
    }
    red[tid*4+0] = ls.x; red[tid*4+1] = ls.y; red[tid*4+2] = ls.z; red[tid*4+3] = ls.w;
    __syncthreads();
    if (tid < 32) {
        int gj = tid >> 2, comp = tid & 3;
        float s = 0.f;
        for (int r = 0; r < 32; r++) s += red[(r * 8 + gj) * 4 + comp];
        atomicAdd(&dacc[tid], (double)s);
    }
    __syncthreads();
    red[tid*4+0] = lq.x; red[tid*4+1] = lq.y; red[tid*4+2] = lq.z; red[tid*4+3] = lq.w;
    __syncthreads();
    if (tid < 32) {
        int gj = tid >> 2, comp = tid & 3;
        float s = 0.f;
        for (int r = 0; r < 32; r++) s += red[(r * 8 + gj) * 4 + comp];
        atomicAdd(&dacc[32 + tid], (double)s);
    }
}

// ---------------- finalize BN stats from double accumulators (tiny) ----------------
__global__ void stats_finalize(const double* __restrict__ dacc, double cntH, double cntE,
                               const float* __restrict__ gH, const float* __restrict__ bH,
                               const float* __restrict__ gE, const float* __restrict__ bE,
                               float* __restrict__ stats)
{
    int tid = threadIdx.x;
    const double* p = dacc + blockIdx.x * 64;
    double cnt = blockIdx.x ? cntE : cntH;
    const float* g = blockIdx.x ? gE : gH;
    const float* b = blockIdx.x ? bE : bH;
    float* outp = stats + blockIdx.x * 64;
    if (tid < 32) {
        double mean = p[tid] / cnt;
        double var = p[32 + tid] / cnt - mean * mean;
        float scale = g[tid] * (float)(1.0 / sqrt(var + 1e-5));
        outp[tid] = scale;
        outp[32 + tid] = b[tid] - (float)mean * scale;
    }
}

// ---------------- apply (h, float4): acc += relu(pre*scale + shift) ----------------
__global__ void apply4(const float4* __restrict__ pre, const float* __restrict__ scale,
                       const float* __restrict__ shift, float4* __restrict__ acc, size_t n4)
{
    size_t i = (size_t)blockIdx.x * 256 + threadIdx.x;
    if (i < n4) {
        int j4 = (int)(i & 7) * 4;
        float4 sc = *(const float4*)(scale + j4);
        float4 sh = *(const float4*)(shift + j4);
        float4 p = pre[i], a = acc[i];
        a.x += fmaxf(fmaf(p.x, sc.x, sh.x), 0.f);
        a.y += fmaxf(fmaf(p.y, sc.y, sh.y), 0.f);
        a.z += fmaxf(fmaf(p.z, sc.z, sh.z), 0.f);
        a.w += fmaxf(fmaf(p.w, sc.w, sh.w), 0.f);
        acc[i] = a;
    }
}

// ---- edge pass 2: recompute e_new (same FMA order), apply BN+ReLU+residual in place ----
__global__ __launch_bounds__(256) void apply_e_fused(
    float* __restrict__ e, const int* __restrict__ srcs, const int* __restrict__ dsts,
    const float* __restrict__ Ah, const float* __restrict__ Bh,
    const float* __restrict__ Cw, const float* __restrict__ Cb,
    const float* __restrict__ sc, const float* __restrict__ sh, int E)
{
    __shared__ float le[256];
    __shared__ int lsrc[8], ldst[8];
    int tid = threadIdx.x, j = tid & 31, el = tid >> 5;
    float cw[32];
#pragma unroll
    for (int k = 0; k < 32; k++) cw[k] = Cw[k * 32 + j];
    float cb = Cb[j];
    float scale = sc[j], shift = sh[j];
    int ng = (E + 7) >> 3;
    for (int g = blockIdx.x; g < ng; g += gridDim.x) {
        int base = g << 3;
        __syncthreads();
        if (tid < 64) {
            int row = base + (tid >> 3);
            if (row < E) ((float4*)le)[tid] = ((const float4*)(e + (size_t)base * 32))[tid];
        }
        if (tid < 8) {
            int ee = base + tid;
            if (ee < E) { lsrc[tid] = srcs[ee]; ldst[tid] = dsts[ee]; }
        }
        __syncthreads();
        int eid = base + el;
        if (eid < E) {
            const float4* lr = (const float4*)(le + el * 32);
            float acc = cb;
#pragma unroll
            for (int q = 0; q < 8; q++) {
                float4 ev = lr[q];
                acc = fmaf(ev.x, cw[4*q],   acc);
                acc = fmaf(ev.y, cw[4*q+1], acc);
                acc = fmaf(ev.z, cw[4*q+2], acc);
                acc = fmaf(ev.w, cw[4*q+3], acc);
            }
            int s = lsrc[el], d = ldst[el];
            float en = acc + Ah[(size_t)d * 32 + j] + Bh[(size_t)s * 32 + j];
            float v = fmaf(en, scale, shift);
            e[(size_t)eid * 32 + j] = le[el * 32 + j] + fmaxf(v, 0.f);
        }
    }
}

// ---------------- predictor: one edge per thread, scalar-broadcast W1/W2 ----------------
__global__ __launch_bounds__(256) void predictor(
    const float* __restrict__ h, const float* __restrict__ e,
    const int* __restrict__ srcs, const int* __restrict__ dsts,
    const float* __restrict__ W1, const float* __restrict__ b1,
    const float* __restrict__ W2, const float* __restrict__ b2v,
    float* __restrict__ out, int E)
{
    int eid = blockIdx.x * 256 + threadIdx.x;
    if (eid >= E) return;
    int s = srcs[eid], d = dsts[eid];
    float acc[32];
#pragma unroll
    for (int j = 0; j < 32; j++) acc[j] = b1[j];          // uniform -> s_load
    const float* zs = h + (size_t)s * 32;
    const float* zd = h + (size_t)d * 32;
    const float* ze = e + (size_t)eid * 32;
#pragma unroll 4
    for (int k = 0; k < 32; k++) {
        float zk = zs[k];
#pragma unroll
        for (int j = 0; j < 32; j++) acc[j] = fmaf(zk, W1[k * 32 + j], acc[j]);
    }
#pragma unroll 4
    for (int k = 0; k < 32; k++) {
        float zk = zd[k];
#pragma unroll
        for (int j = 0; j < 32; j++) acc[j] = fmaf(zk, W1[(32 + k) * 32 + j], acc[j]);
    }
#pragma unroll 4
    for (int k = 0; k < 32; k++) {
        float zk = ze[k];
#pragma unroll
        for (int j = 0; j < 32; j++) acc[j] = fmaf(zk, W1[(64 + k) * 32 + j], acc[j]);
    }
    float t = b2v[0];
#pragma unroll
    for (int j = 0; j < 32; j++) t += fmaxf(acc[j], 0.f) * W2[j];
    out[eid] = t;
}

extern "C" void kernel_launch(void* const* d_in, const int* in_sizes, int n_in,
                              void* d_out, int out_size, void* d_ws, size_t ws_size,
                              hipStream_t stream)
{
    const int N = in_sizes[0];
    const int E = in_sizes[1];

    const float* x    = (const float*)d_in[0];
    const float* e_in = (const float*)d_in[1];
    const int*   eidx = (const int*)d_in[2];
    const float* pe_w = (const float*)d_in[3];
    const float* pe_b = (const float*)d_in[4];
    const float* ed_w = (const float*)d_in[5];
    const float* ed_b = (const float*)d_in[6];
    const float* Aw = (const float*)d_in[7];
    const float* Ab = (const float*)d_in[8];
    const float* Bw = (const float*)d_in[9];
    const float* Bb = (const float*)d_in[10];
    const float* Cw = (const float*)d_in[11];
    const float* Cb = (const float*)d_in[12];
    const float* Uw = (const float*)d_in[13];
    const float* Ub = (const float*)d_in[14];
    const float* Vw = (const float*)d_in[15];
    const float* Vb = (const float*)d_in[16];
    const float* bn_h_g = (const float*)d_in[17];
    const float* bn_h_b = (const float*)d_in[18];
    const float* bn_e_g = (const float*)d_in[19];
    const float* bn_e_b = (const float*)d_in[20];
    const float* W1w = (const float*)d_in[21];
    const float* W1b = (const float*)d_in[22];
    const float* W2w = (const float*)d_in[23];
    const float* W2b = (const float*)d_in[24];

    const int* srcs = eidx;
    const int* dsts = eidx + E;

    size_t nh = (size_t)N * 32;
    size_t eh = (size_t)E * 32;

    float* ws = (float*)d_ws;
    float* h    = ws;
    float* Ah   = h + nh;
    float* Bh   = Ah + nh;
    float* Uh   = Bh + nh;
    float* Vh   = Uh + nh;
    float* num  = Vh + nh;        // doubles as hnew (in-place)
    float* den  = num + nh;       // num & den & dacc contiguous for one zero-fill
    double* dacc = (double*)(den + nh);  // 128 doubles: h_sum[32],h_sq[32],e_sum[32],e_sq[32]
    float* e    = (float*)(dacc + 128);
    float* stats = e + eh;        // sc_h[32],sh_h[32],sc_e[32],sh_e[32]

    size_t nh4 = nh / 4, eh4 = eh / 4;
    int gh4 = (int)((nh4 + 255) / 256);
    int ge4 = (int)((eh4 + 255) / 256);

    init_proj4<<<gh4, 256, 0, stream>>>(x, pe_w, pe_b, (float4*)h, nh4);
    init_proj4<<<ge4, 256, 0, stream>>>(e_in, ed_w, ed_b, (float4*)e, eh4);

    for (int l = 0; l < NLAYERS; l++) {
        // zero num, den, and the 128-double accumulator in one pass
        zero_kernel<<<1024, 256, 0, stream>>>((float4*)num, (2 * nh + 256) / 4);
        node_gemm<<<(N + 63) / 64, 64, 0, stream>>>(h,
            Aw + l * 1024, Ab + l * 32,
            Bw + l * 1024, Bb + l * 32,
            Uw + l * 1024, Ub + l * 32,
            Vw + l * 1024, Vb + l * 32,
            Ah, Bh, Uh, Vh, N);
        edge_kernel<<<4096, 256, 0, stream>>>(e, srcs, dsts, Ah, Bh, Vh,
            Cw + l * 1024, Cb + l * 32, num, den, dacc + 64, E);
        node_update<<<2048, 256, 0, stream>>>((const float4*)Uh, (float4*)num, (const float4*)den,
            dacc, N);
        stats_finalize<<<2, 64, 0, stream>>>(dacc, (double)N, (double)E,
            bn_h_g + l * 32, bn_h_b + l * 32, bn_e_g + l * 32, bn_e_b + l * 32, stats);
        apply4<<<gh4, 256, 0, stream>>>((const float4*)num, stats + 0, stats + 32, (float4*)h, nh4);
        apply_e_fused<<<4096, 256, 0, stream>>>(e, srcs, dsts, Ah, Bh,
            Cw + l * 1024, Cb + l * 32, stats + 64, stats + 96, E);
    }

    predictor<<<(E + 255) / 256, 256, 0, stream>>>(h, e, srcs, dsts, W1w, W1b, W2w, W2b,
                                                   (float*)d_out, E);
}